// Round 8
// baseline (419.108 us; speedup 1.0000x reference)
//
#include <hip/hip_runtime.h>

typedef __bf16 bf16;
typedef __bf16 bf16x4 __attribute__((ext_vector_type(4)));
typedef __bf16 bf16x8 __attribute__((ext_vector_type(8)));
typedef float  fx4    __attribute__((ext_vector_type(4)));

#define MFMA16(a, b, c) __builtin_amdgcn_mfma_f32_16x16x32_bf16((a), (b), (c), 0, 0, 0)

// B=4, N=2048, E=768, H=8, D=96; M = B*N = 8192. User tensors fp32, out fp32.

// ---------------------------------------------------------------------------
// fp32 -> bf16, 4 elems/thread (used for x and, ws permitting, the weights).
// ---------------------------------------------------------------------------
__global__ __launch_bounds__(256)
void cvt_kernel(const float* __restrict__ x, bf16* __restrict__ xb) {
  const int i = (blockIdx.x * 256 + threadIdx.x) * 4;
  float4 v = *(const float4*)&x[i];
  bf16x4 o;
  o[0] = (bf16)v.x; o[1] = (bf16)v.y; o[2] = (bf16)v.z; o[3] = (bf16)v.w;
  *(bf16x4*)&xb[i] = o;
}

// ---------------------------------------------------------------------------
// Fused QKV GEMM: 1152 blocks = 4.5/CU. blockIdx.x: 0-5 Q, 6-11 K, 12-17 V
// (V transposed out). Tile 128x128, BK=32, 4 waves 2x2, 4x4 MFMAs.
// Wb (nullable): pre-converted bf16 weights [Wq|Wk|Wv] -> uint4 staging.
// ---------------------------------------------------------------------------
__global__ __launch_bounds__(256)
void gemm_qkv(const bf16* __restrict__ A,
              const float* __restrict__ Wq, const float* __restrict__ Wk,
              const float* __restrict__ Wv,
              const float* __restrict__ bq, const float* __restrict__ bk,
              const float* __restrict__ bv,
              const bf16* __restrict__ Wb,
              bf16* __restrict__ Qo, bf16* __restrict__ Ko,
              bf16* __restrict__ Vto) {
  constexpr int K = 768;
  __shared__ __align__(16) bf16 As[128 * 32];
  __shared__ __align__(16) bf16 Bs[128 * 32];

  const int tid  = threadIdx.x;
  const int wave = tid >> 6;
  const int lane = tid & 63;
  const int l15  = lane & 15;
  const int q4   = lane >> 4;
  const int wr   = wave >> 1;
  const int wc   = wave & 1;
  const int sel  = blockIdx.x / 6;            // 0=Q 1=K 2=V (block-uniform)
  const int cb0  = (blockIdx.x % 6) * 128;
  const int rb0  = blockIdx.y * 128;

  const float* W   = (sel == 0) ? Wq : (sel == 1) ? Wk : Wv;
  const float* bia = (sel == 0) ? bq : (sel == 1) ? bk : bv;
  const bf16*  Wbs = Wb ? Wb + (size_t)sel * 768 * 768 : nullptr;

  fx4 acc[4][4];
#pragma unroll
  for (int i = 0; i < 4; i++)
#pragma unroll
    for (int j = 0; j < 4; j++) acc[i][j] = (fx4){0.f, 0.f, 0.f, 0.f};

  for (int k0 = 0; k0 < K; k0 += 32) {
    for (int c = tid; c < 512; c += 256) {
      const int row = c >> 2;
      const int kc  = (c & 3) << 3;
      *(uint4*)&As[row * 32 + kc] =
          *(const uint4*)&A[(size_t)(rb0 + row) * K + k0 + kc];
      if (Wbs) {
        *(uint4*)&Bs[row * 32 + kc] =
            *(const uint4*)&Wbs[(size_t)(cb0 + row) * K + k0 + kc];
      } else {
        const float* sb = W + (size_t)(cb0 + row) * K + k0 + kc;
        bf16x8 pb;
#pragma unroll
        for (int t = 0; t < 8; t++) pb[t] = (bf16)sb[t];
        *(bf16x8*)&Bs[row * 32 + kc] = pb;
      }
    }
    __syncthreads();

    bf16x8 a[4], b[4];
#pragma unroll
    for (int i = 0; i < 4; i++)
      a[i] = *(const bf16x8*)&As[(wr * 64 + i * 16 + l15) * 32 + q4 * 8];
#pragma unroll
    for (int j = 0; j < 4; j++)
      b[j] = *(const bf16x8*)&Bs[(wc * 64 + j * 16 + l15) * 32 + q4 * 8];
#pragma unroll
    for (int i = 0; i < 4; i++)
#pragma unroll
      for (int j = 0; j < 4; j++)
        acc[i][j] = MFMA16(a[i], b[j], acc[i][j]);
    __syncthreads();
  }

  const int cb = cb0 + wc * 64;
  const int rb = rb0 + wr * 64;
  bf16* Co = (sel == 0) ? Qo : Ko;
#pragma unroll
  for (int j = 0; j < 4; j++) {
    const int o  = cb + j * 16 + l15;
    const float bj = bia[o];
#pragma unroll
    for (int i = 0; i < 4; i++) {
      const int r0 = rb + i * 16 + q4 * 4;
      if (sel == 2) {
        const int bb = r0 >> 11;
        const int n0 = r0 & 2047;
        bf16x4 pk;
#pragma unroll
        for (int r = 0; r < 4; r++) pk[r] = (bf16)(acc[i][j][r] + bj);
        *(bf16x4*)&Vto[((size_t)(bb * 768 + o)) * 2048 + n0] = pk;
      } else {
#pragma unroll
        for (int r = 0; r < 4; r++)
          Co[(size_t)(r0 + r) * 768 + o] = (bf16)(acc[i][j][r] + bj);
      }
    }
  }
}

// ---------------------------------------------------------------------------
// Output projection: out fp32 = (A + A2?) @ Wo^T + bo. A2 nullable (k-split
// partial combine happens in staging). Wb nullable (bf16 Wo).
// ---------------------------------------------------------------------------
__global__ __launch_bounds__(256)
void gemm_o(const bf16* __restrict__ A, const bf16* __restrict__ A2,
            const float* __restrict__ W, const bf16* __restrict__ Wb,
            const float* __restrict__ bias, float* __restrict__ C) {
  constexpr int K = 768;
  __shared__ __align__(16) bf16 As[128 * 32];
  __shared__ __align__(16) bf16 Bs[128 * 32];

  const int tid  = threadIdx.x;
  const int wave = tid >> 6;
  const int lane = tid & 63;
  const int l15  = lane & 15;
  const int q4   = lane >> 4;
  const int wr   = wave >> 1;
  const int wc   = wave & 1;
  const int rb0  = blockIdx.y * 128;
  const int cb0  = blockIdx.x * 128;

  fx4 acc[4][4];
#pragma unroll
  for (int i = 0; i < 4; i++)
#pragma unroll
    for (int j = 0; j < 4; j++) acc[i][j] = (fx4){0.f, 0.f, 0.f, 0.f};

  for (int k0 = 0; k0 < K; k0 += 32) {
    for (int c = tid; c < 512; c += 256) {
      const int row = c >> 2;
      const int kc  = (c & 3) << 3;
      const size_t off = (size_t)(rb0 + row) * K + k0 + kc;
      if (A2) {
        bf16x8 p1 = *(const bf16x8*)&A[off];
        bf16x8 p2 = *(const bf16x8*)&A2[off];
        bf16x8 ps;
#pragma unroll
        for (int t = 0; t < 8; t++) ps[t] = (bf16)((float)p1[t] + (float)p2[t]);
        *(bf16x8*)&As[row * 32 + kc] = ps;
      } else {
        *(uint4*)&As[row * 32 + kc] = *(const uint4*)&A[off];
      }
      if (Wb) {
        *(uint4*)&Bs[row * 32 + kc] =
            *(const uint4*)&Wb[(size_t)(cb0 + row) * K + k0 + kc];
      } else {
        const float* sb = W + (size_t)(cb0 + row) * K + k0 + kc;
        bf16x8 pb;
#pragma unroll
        for (int t = 0; t < 8; t++) pb[t] = (bf16)sb[t];
        *(bf16x8*)&Bs[row * 32 + kc] = pb;
      }
    }
    __syncthreads();

    bf16x8 a[4], b[4];
#pragma unroll
    for (int i = 0; i < 4; i++)
      a[i] = *(const bf16x8*)&As[(wr * 64 + i * 16 + l15) * 32 + q4 * 8];
#pragma unroll
    for (int j = 0; j < 4; j++)
      b[j] = *(const bf16x8*)&Bs[(wc * 64 + j * 16 + l15) * 32 + q4 * 8];
#pragma unroll
    for (int i = 0; i < 4; i++)
#pragma unroll
      for (int j = 0; j < 4; j++)
        acc[i][j] = MFMA16(a[i], b[j], acc[i][j]);
    __syncthreads();
  }

  const int cb = cb0 + wc * 64;
  const int rb = rb0 + wr * 64;
#pragma unroll
  for (int j = 0; j < 4; j++) {
    const int o  = cb + j * 16 + l15;
    const float bj = bias[o];
#pragma unroll
    for (int i = 0; i < 4; i++) {
      const int r0 = rb + i * 16 + q4 * 4;
#pragma unroll
      for (int r = 0; r < 4; r++)
        C[(size_t)(r0 + r) * 768 + o] = acc[i][j][r] + bj;
    }
  }
}

// ---------------------------------------------------------------------------
// Attention, softmax over HEADS (dim=1), / sqrt(768). Round-7 structure
// (wave=head, TQ=32, batched K/V loads, LDS cross-head softmax, 2 barriers).
// K-SPLIT: softmax has no coupling along k, so O = sum_k P.V splits across
// key ranges. Grid = 256*NS blocks; split s handles kt in [s*ktn, s*ktn+ktn)
// and writes its bf16 partial to AOs[s]. NS=2 -> 2 blocks/CU (the round-7
// limiter was grid=256 = 1 block/CU: every barrier stalled the whole CU).
// AO0 may alias Q ONLY when NS=1 (split mode has cross-block Q reads).
// ---------------------------------------------------------------------------
__global__ __launch_bounds__(512, 2)
void attn_kernel(const bf16* Q, const bf16* __restrict__ Kb,
                 const bf16* __restrict__ Vt, bf16* AO0, bf16* AO1, int ktn) {
  __shared__ __align__(16) float Ebuf[32 * 260];     // [q][h*32+k], 33.3 KB
  __shared__ __align__(16) bf16  Pbuf[8 * 32 * 32];  // [h][q][k],   16 KB

  const int tid  = threadIdx.x;
  const int h    = tid >> 6;
  const int lane = tid & 63;
  const int l15  = lane & 15;
  const int q4   = lane >> 4;
  const int bidx = blockIdx.x & 255;
  const int s    = blockIdx.x >> 8;        // split index
  const int b    = bidx >> 6;
  const int qt   = bidx & 63;
  const int qrow0 = b * 2048 + qt * 32;
  bf16* AO = s ? AO1 : AO0;

  bf16x8 aq[2][3];
#pragma unroll
  for (int i = 0; i < 2; i++)
#pragma unroll
    for (int c = 0; c < 3; c++)
      aq[i][c] = *(const bf16x8*)
          &Q[(size_t)(qrow0 + i * 16 + l15) * 768 + h * 96 + c * 32 + q4 * 8];

  fx4 o[2][6];
#pragma unroll
  for (int i = 0; i < 2; i++)
#pragma unroll
    for (int j = 0; j < 6; j++) o[i][j] = (fx4){0.f, 0.f, 0.f, 0.f};

  const bf16* Kp0 = Kb + (size_t)(b * 2048 + l15) * 768 + h * 96 + q4 * 8;
  const bf16* Vp0 = Vt + (size_t)((b * 8 + h) * 96 + l15) * 2048 + q4 * 8;

  const int kt0 = s * ktn;
  for (int kt = kt0; kt < kt0 + ktn; kt++) {
    // Batched loads: 6 K + 6 V fragments, all in flight together.
    bf16x8 bk[2][3], bv[6];
    const bf16* Kp = Kp0 + (size_t)(kt * 32) * 768;
#pragma unroll
    for (int j = 0; j < 2; j++)
#pragma unroll
      for (int c = 0; c < 3; c++)
        bk[j][c] = *(const bf16x8*)(Kp + (size_t)(j * 16) * 768 + c * 32);
#pragma unroll
    for (int j2 = 0; j2 < 6; j2++)
      bv[j2] = *(const bf16x8*)(Vp0 + (size_t)(j2 * 16) * 2048 + kt * 32);

    // E = Q K^T : [32q x 32k] for this head.
    fx4 e[2][2];
    e[0][0] = e[0][1] = e[1][0] = e[1][1] = (fx4){0.f, 0.f, 0.f, 0.f};
#pragma unroll
    for (int c = 0; c < 3; c++)
#pragma unroll
      for (int j = 0; j < 2; j++) {
        e[0][j] = MFMA16(aq[0][c], bk[j][c], e[0][j]);
        e[1][j] = MFMA16(aq[1][c], bk[j][c], e[1][j]);
      }

#pragma unroll
    for (int i = 0; i < 2; i++)
#pragma unroll
      for (int j = 0; j < 2; j++)
#pragma unroll
        for (int r = 0; r < 4; r++)
          Ebuf[(i * 16 + q4 * 4 + r) * 260 + h * 32 + j * 16 + l15] = e[i][j][r];
    __syncthreads();

    // Softmax over heads. 1024 (q,k) pairs, 2 per thread.
#pragma unroll
    for (int pp = 0; pp < 2; pp++) {
      const int p = tid + pp * 512;
      const int q = p >> 5, k = p & 31;
      float v[8];
#pragma unroll
      for (int hh = 0; hh < 8; hh++) v[hh] = Ebuf[q * 260 + hh * 32 + k];
      float m = v[0];
#pragma unroll
      for (int hh = 1; hh < 8; hh++) m = fmaxf(m, v[hh]);
      float sm = 0.f;
#pragma unroll
      for (int hh = 0; hh < 8; hh++) { v[hh] = __expf(v[hh] - m); sm += v[hh]; }
      const float inv = 1.0f / (sm * 27.712812921102035f);  // / sqrt(768)
#pragma unroll
      for (int hh = 0; hh < 8; hh++)
        Pbuf[hh * 1024 + q * 32 + k] = (bf16)(v[hh] * inv);
    }
    __syncthreads();

    // O += P @ V (V already in registers).
    bf16x8 ap[2];
#pragma unroll
    for (int i = 0; i < 2; i++)
      ap[i] = *(const bf16x8*)&Pbuf[h * 1024 + (i * 16 + l15) * 32 + q4 * 8];
#pragma unroll
    for (int j2 = 0; j2 < 6; j2++) {
      o[0][j2] = MFMA16(ap[0], bv[j2], o[0][j2]);
      o[1][j2] = MFMA16(ap[1], bv[j2], o[1][j2]);
    }
  }

  // Write partial (or full) AO[qrow0 + q][h*96 + d]
#pragma unroll
  for (int i = 0; i < 2; i++)
#pragma unroll
    for (int j2 = 0; j2 < 6; j2++)
#pragma unroll
      for (int r = 0; r < 4; r++)
        AO[(size_t)(qrow0 + i * 16 + q4 * 4 + r) * 768 + h * 96 + j2 * 16 + l15] =
            (bf16)(o[i][j2][r]);
}

// ---------------------------------------------------------------------------
// Memory plan, tiered on ws_size (deterministic across calls -> graph-safe):
//   base (25.2 MB):  Q, Vt in ws; d_out = xb + Kw (both dead before gemm_o).
//   T1   (50.3 MB): + AO0, AO1 -> attention k-split S=2 (2 blocks/CU).
//   T2   (55.1 MB): + Wb: weights pre-converted to bf16 (uint4 GEMM staging).
// Fallback: AO aliases Q (proven safe when NS=1).
// ---------------------------------------------------------------------------
extern "C" void kernel_launch(void* const* d_in, const int* in_sizes, int n_in,
                              void* d_out, int out_size, void* d_ws,
                              size_t ws_size, hipStream_t stream) {
  const float* x  = (const float*)d_in[0];
  const float* Wq = (const float*)d_in[1];
  const float* bq = (const float*)d_in[2];
  const float* Wk = (const float*)d_in[3];
  const float* bk = (const float*)d_in[4];
  const float* Wv = (const float*)d_in[5];
  const float* bv = (const float*)d_in[6];
  const float* Wo = (const float*)d_in[7];
  const float* bo = (const float*)d_in[8];

  const size_t MN = (size_t)8192 * 768;
  const size_t WN = (size_t)768 * 768;
  bf16* xb = (bf16*)d_out;
  bf16* Kw = xb + MN;
  bf16* Q  = (bf16*)d_ws;
  bf16* Vt = Q + MN;

  const bool split = ws_size >= 4 * MN * sizeof(bf16);               // 50.3 MB
  const bool wbf   = ws_size >= (4 * MN + 4 * WN) * sizeof(bf16);    // 55.1 MB

  bf16* AO0 = split ? Vt + MN : Q;    // non-split: alias Q (proven)
  bf16* AO1 = split ? AO0 + MN : Q;
  bf16* Wb  = wbf ? AO0 + 2 * MN : nullptr;   // [Wq|Wk|Wv|Wo] bf16

  cvt_kernel<<<6144, 256, 0, stream>>>(x, xb);
  if (wbf) {
    cvt_kernel<<<576, 256, 0, stream>>>(Wq, Wb + 0 * WN);
    cvt_kernel<<<576, 256, 0, stream>>>(Wk, Wb + 1 * WN);
    cvt_kernel<<<576, 256, 0, stream>>>(Wv, Wb + 2 * WN);
    cvt_kernel<<<576, 256, 0, stream>>>(Wo, Wb + 3 * WN);
  }

  dim3 qkvgrid(18, 64);
  gemm_qkv<<<qkvgrid, 256, 0, stream>>>(xb, Wq, Wk, Wv, bq, bk, bv, Wb,
                                        Q, Kw, Vt);

  if (split) {
    attn_kernel<<<512, 512, 0, stream>>>(Q, Kw, Vt, AO0, AO1, 32);
  } else {
    attn_kernel<<<256, 512, 0, stream>>>(Q, Kw, Vt, AO0, AO0, 64);
  }

  dim3 ogrid(6, 64);
  gemm_o<<<ogrid, 256, 0, stream>>>(AO0, split ? AO1 : nullptr, Wo,
                                    wbf ? Wb + 3 * WN : nullptr, bo,
                                    (float*)d_out);
}